// Round 6
// baseline (431.888 us; speedup 1.0000x reference)
//
#include <hip/hip_runtime.h>
#include <hip/hip_bf16.h>
#include <cstdint>
#include <cstddef>

#define HH 1024
#define BB 8
#define TT 2048
#define MM (BB*TT)   // 16384
#define CC 128       // wkv chunks
#define LL (TT/CC)   // 16 steps per chunk

typedef __attribute__((ext_vector_type(8))) short bf16x8;
typedef __attribute__((ext_vector_type(8))) unsigned short u16x8;
typedef __attribute__((ext_vector_type(4))) float f32x4;

__device__ __forceinline__ unsigned short f2bf(float f) {
  union { float f; unsigned u; } v; v.f = f;
  return (unsigned short)((v.u + 0x7fffu + ((v.u >> 16) & 1u)) >> 16);  // RNE
}
__device__ __forceinline__ float bf2f(unsigned short s) {
  union { float f; unsigned u; } v; v.u = ((unsigned)s) << 16;
  return v.f;
}

__device__ __forceinline__ void load_lds16(const void* g, void* l) {
  __builtin_amdgcn_global_load_lds((const __attribute__((address_space(1))) void*)g,
                                   (__attribute__((address_space(3))) void*)l,
                                   16, 0, 0);
}

// ---------------- weight fp32 -> bf16 ----------------
__global__ __launch_bounds__(256) void conv_w(const float* __restrict__ Wk,
    const float* __restrict__ Wv, const float* __restrict__ Wr,
    const float* __restrict__ Wo, unsigned short* __restrict__ dst) {
  const int i = (blockIdx.x * 256 + threadIdx.x) * 4;
  const float* src = blockIdx.y == 0 ? Wk : blockIdx.y == 1 ? Wv : blockIdx.y == 2 ? Wr : Wo;
  const float4 v = *(const float4*)(src + i);
  ushort4 o; o.x = f2bf(v.x); o.y = f2bf(v.y); o.z = f2bf(v.z); o.w = f2bf(v.w);
  *(ushort4*)(dst + (size_t)blockIdx.y * HH * HH + i) = o;
}

// ---------------- time-shift + mix -> bf16 kin/vin/rin ----------------
__global__ __launch_bounds__(256) void mix_kernel(const float* __restrict__ x,
    const float* __restrict__ tmk, const float* __restrict__ tmv, const float* __restrict__ tmr,
    unsigned short* __restrict__ kin, unsigned short* __restrict__ vin,
    unsigned short* __restrict__ rin) {
  const int gid = blockIdx.x * 256 + threadIdx.x;
  const size_t e0 = (size_t)gid * 4;
  const int h = (int)(e0 & (HH - 1));
  const int t = (int)((e0 >> 10) & (TT - 1));
  const float4 xv = *(const float4*)(x + e0);
  float4 sv = make_float4(0.f, 0.f, 0.f, 0.f);
  if (t != 0) sv = *(const float4*)(x + e0 - HH);
  const float4 k4 = *(const float4*)(tmk + h);
  const float4 v4 = *(const float4*)(tmv + h);
  const float4 r4 = *(const float4*)(tmr + h);
  ushort4 ko, vo, ro;
  ko.x = f2bf(sv.x + k4.x * (xv.x - sv.x)); ko.y = f2bf(sv.y + k4.y * (xv.y - sv.y));
  ko.z = f2bf(sv.z + k4.z * (xv.z - sv.z)); ko.w = f2bf(sv.w + k4.w * (xv.w - sv.w));
  vo.x = f2bf(sv.x + v4.x * (xv.x - sv.x)); vo.y = f2bf(sv.y + v4.y * (xv.y - sv.y));
  vo.z = f2bf(sv.z + v4.z * (xv.z - sv.z)); vo.w = f2bf(sv.w + v4.w * (xv.w - sv.w));
  ro.x = f2bf(sv.x + r4.x * (xv.x - sv.x)); ro.y = f2bf(sv.y + r4.y * (xv.y - sv.y));
  ro.z = f2bf(sv.z + r4.z * (xv.z - sv.z)); ro.w = f2bf(sv.w + r4.w * (xv.w - sv.w));
  *(ushort4*)(kin + e0) = ko;
  *(ushort4*)(vin + e0) = vo;
  *(ushort4*)(rin + e0) = ro;
}

// ============ 256x256 GEMM core, r6: read-ahead pipelined 4-phase ============
// BM=BN=256, BK=64, 8 waves (2M x 4N), LDS 128 KiB, 3-bit block swizzle (0 conflicts).
// r4/r5 lesson: reads feeding the SAME phase's MFMA serialize LDS drain and MFMA
// (lgkm-wait between them) -> MfmaUtil stuck ~35%. r6: each phase's MFMA uses
// fragments read ONE PHASE EARLIER; this phase's reads fill the next phase's regs.
// No lgkm-wait inside a phase -> LDS drain (~1150 cy/CU/phase) hides under the
// MFMA cluster (~1240 cy/SIMD/phase).
//   af: double-buffered (afA/afB alternate per phase, 32+32 VGPR)
//   bfr: single set (32 VGPR); next tile's B reads placed after the last cluster
//        using current B -> compiler's register-WAR interleaves them progressively
//   stages: issued AFTER each phase's BAR (readers of overwritten rows lgkm'd
//        before that barrier -> WAR-safe)
//   vmcnt(0) only at PhB0/PhB1 opens (in-flight there = exactly the 8 loads of the
//        tile first read in that phase); never drained mid-phase
// acc in AGPRs (launch_bounds(512,2) keeps total <= 256/wave, 2 waves/SIMD).

#define BAR()   do { asm volatile("" ::: "memory"); __builtin_amdgcn_s_barrier(); \
                     asm volatile("" ::: "memory"); } while (0)
#define VM4()   asm volatile("s_waitcnt vmcnt(4)" ::: "memory")
#define VM0()   asm volatile("s_waitcnt vmcnt(0)" ::: "memory")
#define PRIO1() __builtin_amdgcn_s_setprio(1)
#define PRIO0() __builtin_amdgcn_s_setprio(0)

__device__ __forceinline__ void stA(const unsigned short* __restrict__ Ag, int m0, int kt,
                                    unsigned short* buf, int h, int w, int rl, int scol) {
#pragma unroll
  for (int l = 0; l < 2; ++l) {
    const int row = l * 128 + h * 64 + w * 8;          // wave-uniform dest row base (0 mod 8)
    load_lds16(Ag + (size_t)(m0 + row + rl) * HH + kt + scol, buf + row * 64);
  }
}
__device__ __forceinline__ void stB(const unsigned short* __restrict__ Bg, int n0, int kt,
                                    unsigned short* buf, int h, int w, int rl, int scol) {
#pragma unroll
  for (int l = 0; l < 2; ++l) {
    const int row = (2 * (l * 2 + (w >> 2)) + h) * 32 + (w & 3) * 8;   // 0 mod 8
    load_lds16(Bg + (size_t)(n0 + row + rl) * HH + kt + scol, buf + row * 64);
  }
}

// read one A half (MH): 8 x ds_read_b128 into the given af set
template<int MH>
__device__ __forceinline__ void rdA(const unsigned short* buf, bf16x8 (&af)[4][2],
                                    int wm, int l15, int kq, int swz) {
#pragma unroll
  for (int fm = 0; fm < 4; ++fm)
#pragma unroll
    for (int kk = 0; kk < 2; ++kk)
      af[fm][kk] = *(const bf16x8*)(buf + (wm * 128 + MH * 64 + fm * 16 + l15) * 64
                                        + ((kk * 32 + kq * 8) ^ swz));
}
// read the full B tile slice for this wave: 8 x ds_read_b128
__device__ __forceinline__ void rdBall(const unsigned short* buf, bf16x8 (&bfr)[2][2][2],
                                       int wn, int l15, int kq, int swz) {
#pragma unroll
  for (int nh = 0; nh < 2; ++nh)
#pragma unroll
    for (int fn = 0; fn < 2; ++fn)
#pragma unroll
      for (int kk = 0; kk < 2; ++kk)
        bfr[nh][fn][kk] = *(const bf16x8*)(buf + (wn * 64 + nh * 32 + fn * 16 + l15) * 64
                                               + ((kk * 32 + kq * 8) ^ swz));
}
// 32 MFMA for one MH half. Operands SWAPPED (bfr first) -> acc = C^T fragments.
// nh-major order so bfr elements die progressively (frees next-B read interleave).
template<int MH>
__device__ __forceinline__ void mfma32(f32x4 (&acc)[8][4], const bf16x8 (&af)[4][2],
                                       const bf16x8 (&bfr)[2][2][2]) {
#pragma unroll
  for (int nh = 0; nh < 2; ++nh)
#pragma unroll
    for (int fn = 0; fn < 2; ++fn)
#pragma unroll
      for (int kk = 0; kk < 2; ++kk)
#pragma unroll
        for (int fm = 0; fm < 4; ++fm)
          acc[MH * 4 + fm][nh * 2 + fn] = __builtin_amdgcn_mfma_f32_16x16x32_bf16(
              bfr[nh][fn][kk], af[fm][kk], acc[MH * 4 + fm][nh * 2 + fn], 0, 0, 0);
}

__device__ __forceinline__ void gemm256(const unsigned short* __restrict__ Ag,
                                        const unsigned short* __restrict__ Bg,
                                        const int m0, const int n0,
                                        unsigned short* As, unsigned short* Bs,
                                        f32x4 (&acc)[8][4]) {
  const int tid = threadIdx.x;
  const int lane = tid & 63;
  const int w = tid >> 6;
  const int wm = w >> 2, wn = w & 3;
  const int l15 = lane & 15, kq = lane >> 4;
  const int swz = (l15 & 7) << 3;                 // read-side XOR (k-block ^= row&7)
  const int rl = lane >> 3;                        // stage dest row-in-8
  const int scol = ((lane & 7) ^ rl) * 8;          // pre-swizzled global source col
  unsigned short* const A0 = As;
  unsigned short* const A1 = As + 256 * 64;
  unsigned short* const B0 = Bs;
  unsigned short* const B1 = Bs + 256 * 64;
  bf16x8 afA[4][2], afB[4][2], bfr[2][2][2];

  // prologue: buf0 tile0 complete (8 loads), buf1 tile1 h0 (4 loads); drain buf0;
  // pre-read PhA0's fragments (afA = A0 mh0, bfr = B0 full).
  stA(Ag, m0, 0, A0, 0, w, rl, scol);
  stB(Bg, n0, 0, B0, 0, w, rl, scol);
  stB(Bg, n0, 0, B0, 1, w, rl, scol);
  stA(Ag, m0, 0, A0, 1, w, rl, scol);
  stA(Ag, m0, 64, A1, 0, w, rl, scol);
  stB(Bg, n0, 64, B1, 0, w, rl, scol);
  VM4();   // oldest 8 (all of buf0 tile0) complete
  BAR();
  rdA<0>(A0, afA, wm, l15, kq, swz);
  rdBall(B0, bfr, wn, l15, kq, swz);

#pragma unroll 1
  for (int i = 0; i < 8; ++i) {
    const int t1  = ((2 * i + 1) * 64) & (HH - 1);   // buf1 current tile
    const int tn0 = ((2 * i + 2) * 64) & (HH - 1);   // buf0 next tile
    const int tn1 = ((2 * i + 3) * 64) & (HH - 1);   // buf1 next tile (wraps @end, harmless)

    // PhA0: MFMA buf0 mh0 (afA, bfr=t0 B); read af-mh1(A0) -> afB
    BAR();
    stB(Bg, n0, t1, B1, 1, w, rl, scol);
    stA(Ag, m0, t1, A1, 1, w, rl, scol);
    rdA<1>(A0, afB, wm, l15, kq, swz);
    PRIO1(); mfma32<0>(acc, afA, bfr); PRIO0();

    // PhB0: MFMA buf0 mh1 (afB, bfr); read buf1: af-mh0 -> afA, then B1 -> bfr
    VM0();   // in-flight = {A1h0,B1h0}(prev PhB1) + {B1h1,A1h1}(PhA0) = buf1 tile complete
    BAR();
    stA(Ag, m0, tn0, A0, 0, w, rl, scol);
    stB(Bg, n0, tn0, B0, 0, w, rl, scol);
    rdA<0>(A1, afA, wm, l15, kq, swz);
    PRIO1(); mfma32<1>(acc, afB, bfr); PRIO0();
    rdBall(B1, bfr, wn, l15, kq, swz);   // reg-WAR chains each read behind its last use

    // PhA1: MFMA buf1 mh0 (afA, bfr=t1 B); read af-mh1(A1) -> afB
    BAR();
    stB(Bg, n0, tn0, B0, 1, w, rl, scol);
    stA(Ag, m0, tn0, A0, 1, w, rl, scol);
    rdA<1>(A1, afB, wm, l15, kq, swz);
    PRIO1(); mfma32<0>(acc, afA, bfr); PRIO0();

    // PhB1: MFMA buf1 mh1 (afB, bfr); read buf0-next: af-mh0 -> afA, then B0 -> bfr
    VM0();   // in-flight = {A0h0,B0h0}(PhB0) + {B0h1,A0h1}(PhA1) = buf0 next tile complete
    BAR();
    stA(Ag, m0, tn1, A1, 0, w, rl, scol);
    stB(Bg, n0, tn1, B1, 0, w, rl, scol);
    rdA<0>(A0, afA, wm, l15, kq, swz);
    PRIO1(); mfma32<1>(acc, afB, bfr); PRIO0();
    rdBall(B0, bfr, wn, l15, kq, swz);
  }
  // no DMA may outlive this workgroup's LDS allocation
  VM0();
}

// XCD-aware swizzle for 256 wgs (0 mod 8 -> bijective): 32 contiguous tiles per XCD.
__device__ __forceinline__ void swizzle_mn256(int x, int& m0, int& n0) {
  const int wg = (x & 7) * 32 + (x >> 3);
  m0 = (wg >> 2) * 256;          // 64 m-tiles
  n0 = (wg & 3) * 256;           // 4 n-tiles
}

// z=0: k -> bf16, z=1: v -> bf16, z=2: r -> sigmoid -> bf16
// acc = C^T fragments: value C[m][n], m = m0+wm*128+fm*16+l15, n = n0+wn*64+fn*16+lq*4+j
__global__ __launch_bounds__(512, 2) void gemm_kvr(const unsigned short* __restrict__ kin,
    const unsigned short* __restrict__ vin, const unsigned short* __restrict__ rin,
    const unsigned short* __restrict__ Wbf,
    unsigned short* __restrict__ kb, unsigned short* __restrict__ vb,
    unsigned short* __restrict__ rb) {
  __shared__ unsigned short As[2 * 256 * 64];
  __shared__ unsigned short Bs[2 * 256 * 64];
  const int z = blockIdx.y;
  const unsigned short* Ag = z == 0 ? kin : (z == 1 ? vin : rin);
  const unsigned short* Bg = Wbf + (size_t)z * HH * HH;
  unsigned short* Cg = z == 0 ? kb : (z == 1 ? vb : rb);
  int m0, n0; swizzle_mn256(blockIdx.x, m0, n0);
  f32x4 acc[8][4] = {};
  gemm256(Ag, Bg, m0, n0, As, Bs, acc);
  const int lane = threadIdx.x & 63, w = threadIdx.x >> 6;
  const int wm = w >> 2, wn = w & 3, l15 = lane & 15, lq = lane >> 4;
  const bool sig = (z == 2);
#pragma unroll
  for (int fm = 0; fm < 8; ++fm) {
    const size_t mrow = (size_t)(m0 + wm * 128 + fm * 16 + l15) * HH;
#pragma unroll
    for (int fn = 0; fn < 4; ++fn) {
      const int ncol = n0 + wn * 64 + fn * 16 + lq * 4;
      float v0 = acc[fm][fn][0], v1 = acc[fm][fn][1];
      float v2 = acc[fm][fn][2], v3 = acc[fm][fn][3];
      if (sig) {
        v0 = 1.0f / (1.0f + __expf(-v0)); v1 = 1.0f / (1.0f + __expf(-v1));
        v2 = 1.0f / (1.0f + __expf(-v2)); v3 = 1.0f / (1.0f + __expf(-v3));
      }
      ushort4 o; o.x = f2bf(v0); o.y = f2bf(v1); o.z = f2bf(v2); o.w = f2bf(v3);
      *(ushort4*)(Cg + mrow + ncol) = o;
    }
  }
}

// out = rwkv @ Wo^T + bo  (fp32 out, float4 stores)
__global__ __launch_bounds__(512, 2) void gemm_o(const unsigned short* __restrict__ Ag,
    const unsigned short* __restrict__ Bg, const float* __restrict__ bias,
    float* __restrict__ C) {
  __shared__ unsigned short As[2 * 256 * 64];
  __shared__ unsigned short Bs[2 * 256 * 64];
  int m0, n0; swizzle_mn256(blockIdx.x, m0, n0);
  f32x4 acc[8][4] = {};
  gemm256(Ag, Bg, m0, n0, As, Bs, acc);
  const int lane = threadIdx.x & 63, w = threadIdx.x >> 6;
  const int wm = w >> 2, wn = w & 3, l15 = lane & 15, lq = lane >> 4;
#pragma unroll
  for (int fm = 0; fm < 8; ++fm) {
    const size_t mrow = (size_t)(m0 + wm * 128 + fm * 16 + l15) * HH;
#pragma unroll
    for (int fn = 0; fn < 4; ++fn) {
      const int ncol = n0 + wn * 64 + fn * 16 + lq * 4;
      const float4 bv = *(const float4*)(bias + ncol);
      float4 ov;
      ov.x = acc[fm][fn][0] + bv.x; ov.y = acc[fm][fn][1] + bv.y;
      ov.z = acc[fm][fn][2] + bv.z; ov.w = acc[fm][fn][3] + bv.w;
      *(float4*)(C + mrow + ncol) = ov;
    }
  }
}

// ---------------- WKV: chunk-parallel scan over T (8-wide vectorized) ----------------
__global__ __launch_bounds__(256) void wkv_part(const unsigned short* __restrict__ k,
    const unsigned short* __restrict__ v, const float* __restrict__ tdec,
    float* __restrict__ pnum, float* __restrict__ pden) {
  const int gid = blockIdx.x * 256 + threadIdx.x;   // 0 .. CC*BB*HH/8-1
  const int h0 = (gid & 127) * 8;
  const int b = (gid >> 7) & (BB - 1);
  const int c = gid >> 10;
  float td[8], num[8], den[8];
#pragma unroll
  for (int j = 0; j < 8; ++j) {
    td[j] = __expf(-__expf(tdec[h0 + j]));
    num[j] = 0.f; den[j] = 0.f;
  }
  size_t idx = (size_t)b * TT * HH + (size_t)(c * LL) * HH + h0;
#pragma unroll 4
  for (int i = 0; i < LL; ++i, idx += HH) {
    const u16x8 k8 = *(const u16x8*)(k + idx);
    const u16x8 v8 = *(const u16x8*)(v + idx);
#pragma unroll
    for (int j = 0; j < 8; ++j) {
      const float ek = __expf(bf2f(k8[j]));
      num[j] = td[j] * num[j] + ek * bf2f(v8[j]);
      den[j] = td[j] * den[j] + ek;
    }
  }
  const size_t o = (size_t)c * (BB * HH) + b * HH + h0;
#pragma unroll
  for (int j = 0; j < 8; ++j) { pnum[o + j] = num[j]; pden[o + j] = den[j]; }
}

__global__ __launch_bounds__(256) void wkv_scan(const float* __restrict__ tdec,
    float* __restrict__ pnum, float* __restrict__ pden) {
  const int bh = blockIdx.x * 256 + threadIdx.x;     // 0..8191
  const int h = bh & (HH - 1);
  const float ed = __expf(tdec[h]);
  const float tdL = __expf(-ed * (float)LL);         // td^LL exactly
  float num = 0.f, den = 0.f;
#pragma unroll 8
  for (int c = 0; c < CC; ++c) {
    const size_t o = (size_t)c * (BB * HH) + bh;
    const float tn = pnum[o], td_ = pden[o];
    pnum[o] = num; pden[o] = den;
    num = tdL * num + tn;
    den = tdL * den + td_;
  }
}

__global__ __launch_bounds__(256) void wkv_final(const unsigned short* __restrict__ k,
    const unsigned short* __restrict__ v, const unsigned short* __restrict__ r,
    const float* __restrict__ tdec, const float* __restrict__ tfst,
    const float* __restrict__ pnum, const float* __restrict__ pden,
    unsigned short* __restrict__ rwkv) {
  const int gid = blockIdx.x * 256 + threadIdx.x;   // 0 .. CC*BB*HH/8-1
  const int h0 = (gid & 127) * 8;
  const int b = (gid >> 7) & (BB - 1);
  const int c = gid >> 10;
  float td[8], etf[8], num[8], den[8];
  const size_t o = (size_t)c * (BB * HH) + b * HH + h0;
#pragma unroll
  for (int j = 0; j < 8; ++j) {
    td[j] = __expf(-__expf(tdec[h0 + j]));
    etf[j] = __expf(tfst[h0 + j]);
    num[j] = pnum[o + j]; den[j] = pden[o + j];
  }
  size_t idx = (size_t)b * TT * HH + (size_t)(c * LL) * HH + h0;
#pragma unroll 2
  for (int i = 0; i < LL; ++i, idx += HH) {
    const u16x8 k8 = *(const u16x8*)(k + idx);
    const u16x8 v8 = *(const u16x8*)(v + idx);
    const u16x8 r8 = *(const u16x8*)(r + idx);
    u16x8 o8;
#pragma unroll
    for (int j = 0; j < 8; ++j) {
      const float ek = __expf(bf2f(k8[j]));
      const float vt = bf2f(v8[j]);
      const float rt = bf2f(r8[j]);
      const float e = ek * etf[j];                   // exp(tf + k) = exp(k)*exp(tf)
      const float inv = __builtin_amdgcn_rcpf(den[j] + e);
      const float outv = (num[j] + e * vt) * inv;
      num[j] = td[j] * num[j] + ek * vt;
      den[j] = td[j] * den[j] + ek;
      o8[j] = f2bf(outv * rt);
    }
    *(u16x8*)(rwkv + idx) = o8;
  }
}

extern "C" void kernel_launch(void* const* d_in, const int* in_sizes, int n_in,
                              void* d_out, int out_size, void* d_ws, size_t ws_size,
                              hipStream_t stream) {
  (void)in_sizes; (void)n_in; (void)out_size; (void)ws_size;
  const float* x    = (const float*)d_in[0];
  const float* tdec = (const float*)d_in[1];
  const float* tfst = (const float*)d_in[2];
  const float* tmk  = (const float*)d_in[3];
  const float* tmv  = (const float*)d_in[4];
  const float* tmr  = (const float*)d_in[5];
  const float* Wk   = (const float*)d_in[6];
  const float* Wv   = (const float*)d_in[7];
  const float* Wr   = (const float*)d_in[8];
  const float* Wo   = (const float*)d_in[9];
  const float* bo   = (const float*)d_in[10];
  float* out = (float*)d_out;

  char* ws = (char*)d_ws;
  const size_t MiB = (size_t)1 << 20;
  unsigned short* Wbf = (unsigned short*)(ws);             //   8 MiB
  unsigned short* kin = (unsigned short*)(ws + 8 * MiB);   //  32 MiB
  unsigned short* vin = (unsigned short*)(ws + 40 * MiB);  //  32 MiB
  unsigned short* rin = (unsigned short*)(ws + 72 * MiB);  //  32 MiB
  unsigned short* rb  = (unsigned short*)(ws + 104 * MiB); //  32 MiB  (peak 136 MiB)
  // k,v bf16 staged in d_out (64 MiB fp32 buffer = 2 x 32 MiB bf16); dead before gemm_o writes.
  unsigned short* kb = (unsigned short*)out;
  unsigned short* vb = kb + (size_t)MM * HH;
  unsigned short* rwkv = kin;                  // kin dead after gemm_kvr
  float* pnum = (float*)(ws + 40 * MiB);       // vin dead after gemm_kvr (4 MiB @ CC=128)
  float* pden = (float*)(ws + 44 * MiB);       // (4 MiB)

  hipLaunchKernelGGL(conv_w, dim3(1024, 4), dim3(256), 0, stream, Wk, Wv, Wr, Wo, Wbf);
  hipLaunchKernelGGL(mix_kernel, dim3(16384), dim3(256), 0, stream,
                     x, tmk, tmv, tmr, kin, vin, rin);
  hipLaunchKernelGGL(gemm_kvr, dim3(256, 3), dim3(512), 0, stream,
                     kin, vin, rin, Wbf, kb, vb, rb);
  hipLaunchKernelGGL(wkv_part, dim3(512), dim3(256), 0, stream,
                     kb, vb, tdec, pnum, pden);
  hipLaunchKernelGGL(wkv_scan, dim3(32), dim3(256), 0, stream,
                     tdec, pnum, pden);
  hipLaunchKernelGGL(wkv_final, dim3(512), dim3(256), 0, stream,
                     kb, vb, rb, tdec, tfst, pnum, pden, rwkv);
  hipLaunchKernelGGL(gemm_o, dim3(256), dim3(512), 0, stream,
                     rwkv, Wbf + (size_t)3 * HH * HH, bo, out);
}

// Round 7
// 360.825 us; speedup vs baseline: 1.1969x; 1.1969x over previous
//
#include <hip/hip_runtime.h>
#include <hip/hip_bf16.h>
#include <cstdint>
#include <cstddef>

#define HH 1024
#define BB 8
#define TT 2048
#define MM (BB*TT)   // 16384
#define CC 128       // wkv chunks
#define LL (TT/CC)   // 16 steps per chunk

typedef __attribute__((ext_vector_type(8))) short bf16x8;
typedef __attribute__((ext_vector_type(8))) unsigned short u16x8;
typedef __attribute__((ext_vector_type(4))) float f32x4;

__device__ __forceinline__ unsigned short f2bf(float f) {
  union { float f; unsigned u; } v; v.f = f;
  return (unsigned short)((v.u + 0x7fffu + ((v.u >> 16) & 1u)) >> 16);  // RNE
}
__device__ __forceinline__ float bf2f(unsigned short s) {
  union { float f; unsigned u; } v; v.u = ((unsigned)s) << 16;
  return v.f;
}

__device__ __forceinline__ void load_lds16(const void* g, void* l) {
  __builtin_amdgcn_global_load_lds((const __attribute__((address_space(1))) void*)g,
                                   (__attribute__((address_space(3))) void*)l,
                                   16, 0, 0);
}

// ---------------- fused prep: time-shift+mix (blocks 0..16383) + weight conv (16384..20479)
__global__ __launch_bounds__(256) void prep(const float* __restrict__ x,
    const float* __restrict__ tmk, const float* __restrict__ tmv, const float* __restrict__ tmr,
    const float* __restrict__ Wk, const float* __restrict__ Wv,
    const float* __restrict__ Wr, const float* __restrict__ Wo,
    unsigned short* __restrict__ kin, unsigned short* __restrict__ vin,
    unsigned short* __restrict__ rin, unsigned short* __restrict__ Wbf) {
  const int bx = blockIdx.x;
  if (bx < 16384) {
    const int gid = bx * 256 + threadIdx.x;
    const size_t e0 = (size_t)gid * 4;
    const int h = (int)(e0 & (HH - 1));
    const int t = (int)((e0 >> 10) & (TT - 1));
    const float4 xv = *(const float4*)(x + e0);
    float4 sv = make_float4(0.f, 0.f, 0.f, 0.f);
    if (t != 0) sv = *(const float4*)(x + e0 - HH);
    const float4 k4 = *(const float4*)(tmk + h);
    const float4 v4 = *(const float4*)(tmv + h);
    const float4 r4 = *(const float4*)(tmr + h);
    ushort4 ko, vo, ro;
    ko.x = f2bf(sv.x + k4.x * (xv.x - sv.x)); ko.y = f2bf(sv.y + k4.y * (xv.y - sv.y));
    ko.z = f2bf(sv.z + k4.z * (xv.z - sv.z)); ko.w = f2bf(sv.w + k4.w * (xv.w - sv.w));
    vo.x = f2bf(sv.x + v4.x * (xv.x - sv.x)); vo.y = f2bf(sv.y + v4.y * (xv.y - sv.y));
    vo.z = f2bf(sv.z + v4.z * (xv.z - sv.z)); vo.w = f2bf(sv.w + v4.w * (xv.w - sv.w));
    ro.x = f2bf(sv.x + r4.x * (xv.x - sv.x)); ro.y = f2bf(sv.y + r4.y * (xv.y - sv.y));
    ro.z = f2bf(sv.z + r4.z * (xv.z - sv.z)); ro.w = f2bf(sv.w + r4.w * (xv.w - sv.w));
    *(ushort4*)(kin + e0) = ko;
    *(ushort4*)(vin + e0) = vo;
    *(ushort4*)(rin + e0) = ro;
  } else {
    const int q = bx - 16384;                 // 0..4095
    const int zz = q >> 10;                   // 0..3
    const float* src = zz == 0 ? Wk : zz == 1 ? Wv : zz == 2 ? Wr : Wo;
    const int i = ((q & 1023) * 256 + threadIdx.x) * 4;
    const float4 v = *(const float4*)(src + i);
    ushort4 o; o.x = f2bf(v.x); o.y = f2bf(v.y); o.z = f2bf(v.z); o.w = f2bf(v.w);
    *(ushort4*)(Wbf + (size_t)zz * HH * HH + i) = o;
  }
}

// ========= 256x256 GEMM core, r7: r4 schedule + compiler-progressive lgkm =========
// BM=BN=256, BK=64, 8 waves (2M x 4N), LDS 128 KiB, 3-bit block swizzle (0 conflicts, r4).
// r4 post-mortem: manual lgkmcnt(0) drained ALL 12 reads before ANY MFMA each phase ->
// LDS pipe (4608 cy/iter) serialized with MFMA (4966 cy/iter) -> 36% MfmaUtil.
// r6 post-mortem: read-ahead via extra reg buffers spilled (arch budget 128, r4 at 124).
// r7 (register-neutral): DELETE the manual lgkm drain; reads stay pinned between the
// same barriers; the compiler inserts PROGRESSIVE per-use lgkmcnt (m97 evidence).
// Reads ordered in consumption order (B first, kk-outer) so the first MFMA waits for
// ~8/12 reads and the last 4 drain under the first 8 MFMAs. Correctness: every read is
// consumed (and thus compiler-drained) within its own phase, before the next barrier ->
// cross-wave stage-WAR timing identical to r4. VM6 at ph4/ph8 (counted vmcnt) unchanged.

#define BAR()   do { asm volatile("" ::: "memory"); __builtin_amdgcn_s_barrier(); \
                     asm volatile("" ::: "memory"); } while (0)
#define VM6()   asm volatile("s_waitcnt vmcnt(6)" ::: "memory")
#define VM0()   asm volatile("s_waitcnt vmcnt(0)" ::: "memory")
#define PRIO1() __builtin_amdgcn_s_setprio(1)
#define PRIO0() __builtin_amdgcn_s_setprio(0)

__device__ __forceinline__ void stA(const unsigned short* __restrict__ Ag, int m0, int kt,
                                    unsigned short* buf, int h, int w, int rl, int scol) {
#pragma unroll
  for (int l = 0; l < 2; ++l) {
    const int row = l * 128 + h * 64 + w * 8;          // wave-uniform dest row base (0 mod 8)
    load_lds16(Ag + (size_t)(m0 + row + rl) * HH + kt + scol, buf + row * 64);
  }
}
__device__ __forceinline__ void stB(const unsigned short* __restrict__ Bg, int n0, int kt,
                                    unsigned short* buf, int h, int w, int rl, int scol) {
#pragma unroll
  for (int l = 0; l < 2; ++l) {
    const int row = (2 * (l * 2 + (w >> 2)) + h) * 32 + (w & 3) * 8;   // 0 mod 8
    load_lds16(Bg + (size_t)(n0 + row + rl) * HH + kt + scol, buf + row * 64);
  }
}

// read one A half (MH), kk-outer (consumption order): 8 x ds_read_b128
template<int MH>
__device__ __forceinline__ void rdA(const unsigned short* buf, bf16x8 (&af)[4][2],
                                    int wm, int l15, int kq, int swz) {
#pragma unroll
  for (int kk = 0; kk < 2; ++kk)
#pragma unroll
    for (int fm = 0; fm < 4; ++fm)
      af[fm][kk] = *(const bf16x8*)(buf + (wm * 128 + MH * 64 + fm * 16 + l15) * 64
                                        + ((kk * 32 + kq * 8) ^ swz));
}
// read one B half (NH), kk-outer: 4 x ds_read_b128
template<int NH>
__device__ __forceinline__ void rdB(const unsigned short* buf, bf16x8 (&bfr)[2][2][2],
                                    int wn, int l15, int kq, int swz) {
#pragma unroll
  for (int kk = 0; kk < 2; ++kk)
#pragma unroll
    for (int fn = 0; fn < 2; ++fn)
      bfr[NH][fn][kk] = *(const bf16x8*)(buf + (wn * 64 + NH * 32 + fn * 16 + l15) * 64
                                             + ((kk * 32 + kq * 8) ^ swz));
}
// 16 MFMA, kk-outer (matches read order). Operands SWAPPED -> acc = C^T fragments.
template<int MH, int NH>
__device__ __forceinline__ void mfmaQ(f32x4 (&acc)[8][4], const bf16x8 (&af)[4][2],
                                      const bf16x8 (&bfr)[2][2][2]) {
#pragma unroll
  for (int kk = 0; kk < 2; ++kk)
#pragma unroll
    for (int fm = 0; fm < 4; ++fm)
#pragma unroll
      for (int fn = 0; fn < 2; ++fn)
        acc[MH * 4 + fm][NH * 2 + fn] = __builtin_amdgcn_mfma_f32_16x16x32_bf16(
            bfr[NH][fn][kk], af[fm][kk], acc[MH * 4 + fm][NH * 2 + fn], 0, 0, 0);
}

__device__ __forceinline__ void gemm256(const unsigned short* __restrict__ Ag,
                                        const unsigned short* __restrict__ Bg,
                                        const int m0, const int n0,
                                        unsigned short* As, unsigned short* Bs,
                                        f32x4 (&acc)[8][4]) {
  const int tid = threadIdx.x;
  const int lane = tid & 63;
  const int w = tid >> 6;
  const int wm = w >> 2, wn = w & 3;
  const int l15 = lane & 15, kq = lane >> 4;
  const int swz = (l15 & 7) << 3;                 // read-side XOR (k-block ^= row&7)
  const int rl = lane >> 3;                        // stage dest row-in-8
  const int scol = ((lane & 7) ^ rl) * 8;          // pre-swizzled global source col
  unsigned short* const A0 = As;
  unsigned short* const A1 = As + 256 * 64;
  unsigned short* const B0 = Bs;
  unsigned short* const B1 = Bs + 256 * 64;
  bf16x8 af[4][2], bfr[2][2][2];

  // prologue: buf0 tile0 (8 loads) + buf1 tile1 {A1h0,B1h0,B1h1} (6 loads); drain buf0.
  stA(Ag, m0, 0, A0, 0, w, rl, scol);
  stB(Bg, n0, 0, B0, 0, w, rl, scol);
  stB(Bg, n0, 0, B0, 1, w, rl, scol);
  stA(Ag, m0, 0, A0, 1, w, rl, scol);
  stA(Ag, m0, 64, A1, 0, w, rl, scol);
  stB(Bg, n0, 64, B1, 0, w, rl, scol);
  stB(Bg, n0, 64, B1, 1, w, rl, scol);
  VM6(); BAR();

#pragma unroll 1
  for (int i = 0; i < 8; ++i) {
    const int tb1 = ((2 * i + 1) * 64) & (HH - 1);  // buf1 current tile (A1h1 staged ph1)
    const int tn0 = ((2 * i + 2) * 64) & (HH - 1);  // buf0 next tile
    const int tn1 = ((2 * i + 3) * 64) & (HH - 1);  // buf1 next tile (wraps @end, harmless)
    // ph1: read B0-nh0 + A0-mh0; stage buf1.A-h1; MFMA (mh0,nh0)
    rdB<0>(B0, bfr, wn, l15, kq, swz);
    rdA<0>(A0, af, wm, l15, kq, swz);
    stA(Ag, m0, tb1, A1, 1, w, rl, scol);
    BAR(); PRIO1(); mfmaQ<0, 0>(acc, af, bfr); PRIO0(); BAR();
    // ph2: read B0-nh1; stage buf0.A-h0; MFMA (mh0,nh1)
    rdB<1>(B0, bfr, wn, l15, kq, swz);
    stA(Ag, m0, tn0, A0, 0, w, rl, scol);
    BAR(); PRIO1(); mfmaQ<0, 1>(acc, af, bfr); PRIO0(); BAR();
    // ph3: read A0-mh1; stage buf0.B-h0; MFMA (mh1,nh1)
    rdA<1>(A0, af, wm, l15, kq, swz);
    stB(Bg, n0, tn0, B0, 0, w, rl, scol);
    BAR(); PRIO1(); mfmaQ<1, 1>(acc, af, bfr); PRIO0(); BAR();
    // ph4: no reads (af/bfr resident); stage buf0.B-h1; counted vmcnt (drains buf1 tile)
    stB(Bg, n0, tn0, B0, 1, w, rl, scol);
    VM6(); BAR(); PRIO1(); mfmaQ<1, 0>(acc, af, bfr); PRIO0(); BAR();
    // ph5: read B1-nh0 + A1-mh0; stage buf0.A-h1; MFMA buf1 (mh0,nh0)
    rdB<0>(B1, bfr, wn, l15, kq, swz);
    rdA<0>(A1, af, wm, l15, kq, swz);
    stA(Ag, m0, tn0, A0, 1, w, rl, scol);
    BAR(); PRIO1(); mfmaQ<0, 0>(acc, af, bfr); PRIO0(); BAR();
    // ph6: read B1-nh1; stage buf1.A-h0; MFMA (mh0,nh1)
    rdB<1>(B1, bfr, wn, l15, kq, swz);
    stA(Ag, m0, tn1, A1, 0, w, rl, scol);
    BAR(); PRIO1(); mfmaQ<0, 1>(acc, af, bfr); PRIO0(); BAR();
    // ph7: read A1-mh1; stage buf1.B-h0; MFMA (mh1,nh1)
    rdA<1>(A1, af, wm, l15, kq, swz);
    stB(Bg, n0, tn1, B1, 0, w, rl, scol);
    BAR(); PRIO1(); mfmaQ<1, 1>(acc, af, bfr); PRIO0(); BAR();
    // ph8: no reads; stage buf1.B-h1; counted vmcnt (drains buf0 next tile)
    stB(Bg, n0, tn1, B1, 1, w, rl, scol);
    VM6(); BAR(); PRIO1(); mfmaQ<1, 0>(acc, af, bfr); PRIO0(); BAR();
  }
  // no DMA may outlive this workgroup's LDS allocation
  VM0();
}

// XCD-aware swizzle for 256 wgs (0 mod 8 -> bijective): 32 contiguous tiles per XCD.
__device__ __forceinline__ void swizzle_mn256(int x, int& m0, int& n0) {
  const int wg = (x & 7) * 32 + (x >> 3);
  m0 = (wg >> 2) * 256;          // 64 m-tiles
  n0 = (wg & 3) * 256;           // 4 n-tiles
}

// z=0: k -> bf16, z=1: v -> bf16, z=2: r -> sigmoid -> bf16
// acc = C^T fragments: C[m][n], m = m0+wm*128+fm*16+l15, n = n0+wn*64+fn*16+lq*4+j
__global__ __launch_bounds__(512, 2) void gemm_kvr(const unsigned short* __restrict__ kin,
    const unsigned short* __restrict__ vin, const unsigned short* __restrict__ rin,
    const unsigned short* __restrict__ Wbf,
    unsigned short* __restrict__ kb, unsigned short* __restrict__ vb,
    unsigned short* __restrict__ rb) {
  __shared__ unsigned short As[2 * 256 * 64];
  __shared__ unsigned short Bs[2 * 256 * 64];
  const int z = blockIdx.y;
  const unsigned short* Ag = z == 0 ? kin : (z == 1 ? vin : rin);
  const unsigned short* Bg = Wbf + (size_t)z * HH * HH;
  unsigned short* Cg = z == 0 ? kb : (z == 1 ? vb : rb);
  int m0, n0; swizzle_mn256(blockIdx.x, m0, n0);
  f32x4 acc[8][4] = {};
  gemm256(Ag, Bg, m0, n0, As, Bs, acc);
  const int lane = threadIdx.x & 63, w = threadIdx.x >> 6;
  const int wm = w >> 2, wn = w & 3, l15 = lane & 15, lq = lane >> 4;
  const bool sig = (z == 2);
#pragma unroll
  for (int fm = 0; fm < 8; ++fm) {
    const size_t mrow = (size_t)(m0 + wm * 128 + fm * 16 + l15) * HH;
#pragma unroll
    for (int fn = 0; fn < 4; ++fn) {
      const int ncol = n0 + wn * 64 + fn * 16 + lq * 4;
      float v0 = acc[fm][fn][0], v1 = acc[fm][fn][1];
      float v2 = acc[fm][fn][2], v3 = acc[fm][fn][3];
      if (sig) {
        v0 = 1.0f / (1.0f + __expf(-v0)); v1 = 1.0f / (1.0f + __expf(-v1));
        v2 = 1.0f / (1.0f + __expf(-v2)); v3 = 1.0f / (1.0f + __expf(-v3));
      }
      ushort4 o; o.x = f2bf(v0); o.y = f2bf(v1); o.z = f2bf(v2); o.w = f2bf(v3);
      *(ushort4*)(Cg + mrow + ncol) = o;
    }
  }
}

// out = rwkv @ Wo^T + bo  (fp32 out, float4 stores)
__global__ __launch_bounds__(512, 2) void gemm_o(const unsigned short* __restrict__ Ag,
    const unsigned short* __restrict__ Bg, const float* __restrict__ bias,
    float* __restrict__ C) {
  __shared__ unsigned short As[2 * 256 * 64];
  __shared__ unsigned short Bs[2 * 256 * 64];
  int m0, n0; swizzle_mn256(blockIdx.x, m0, n0);
  f32x4 acc[8][4] = {};
  gemm256(Ag, Bg, m0, n0, As, Bs, acc);
  const int lane = threadIdx.x & 63, w = threadIdx.x >> 6;
  const int wm = w >> 2, wn = w & 3, l15 = lane & 15, lq = lane >> 4;
#pragma unroll
  for (int fm = 0; fm < 8; ++fm) {
    const size_t mrow = (size_t)(m0 + wm * 128 + fm * 16 + l15) * HH;
#pragma unroll
    for (int fn = 0; fn < 4; ++fn) {
      const int ncol = n0 + wn * 64 + fn * 16 + lq * 4;
      const float4 bv = *(const float4*)(bias + ncol);
      float4 ov;
      ov.x = acc[fm][fn][0] + bv.x; ov.y = acc[fm][fn][1] + bv.y;
      ov.z = acc[fm][fn][2] + bv.z; ov.w = acc[fm][fn][3] + bv.w;
      *(float4*)(C + mrow + ncol) = ov;
    }
  }
}

// ---------------- WKV: chunk-parallel scan over T (8-wide vectorized) ----------------
__global__ __launch_bounds__(256) void wkv_part(const unsigned short* __restrict__ k,
    const unsigned short* __restrict__ v, const float* __restrict__ tdec,
    float* __restrict__ pnum, float* __restrict__ pden) {
  const int gid = blockIdx.x * 256 + threadIdx.x;   // 0 .. CC*BB*HH/8-1
  const int h0 = (gid & 127) * 8;
  const int b = (gid >> 7) & (BB - 1);
  const int c = gid >> 10;
  float td[8], num[8], den[8];
#pragma unroll
  for (int j = 0; j < 8; ++j) {
    td[j] = __expf(-__expf(tdec[h0 + j]));
    num[j] = 0.f; den[j] = 0.f;
  }
  size_t idx = (size_t)b * TT * HH + (size_t)(c * LL) * HH + h0;
#pragma unroll 4
  for (int i = 0; i < LL; ++i, idx += HH) {
    const u16x8 k8 = *(const u16x8*)(k + idx);
    const u16x8 v8 = *(const u16x8*)(v + idx);
#pragma unroll
    for (int j = 0; j < 8; ++j) {
      const float ek = __expf(bf2f(k8[j]));
      num[j] = td[j] * num[j] + ek * bf2f(v8[j]);
      den[j] = td[j] * den[j] + ek;
    }
  }
  const size_t o = (size_t)c * (BB * HH) + b * HH + h0;
#pragma unroll
  for (int j = 0; j < 8; ++j) { pnum[o + j] = num[j]; pden[o + j] = den[j]; }
}

__global__ __launch_bounds__(256) void wkv_scan(const float* __restrict__ tdec,
    float* __restrict__ pnum, float* __restrict__ pden) {
  const int bh = blockIdx.x * 256 + threadIdx.x;     // 0..8191
  const int h = bh & (HH - 1);
  const float ed = __expf(tdec[h]);
  const float tdL = __expf(-ed * (float)LL);         // td^LL exactly
  float num = 0.f, den = 0.f;
#pragma unroll 8
  for (int c = 0; c < CC; ++c) {
    const size_t o = (size_t)c * (BB * HH) + bh;
    const float tn = pnum[o], td_ = pden[o];
    pnum[o] = num; pden[o] = den;
    num = tdL * num + tn;
    den = tdL * den + td_;
  }
}

__global__ __launch_bounds__(256) void wkv_final(const unsigned short* __restrict__ k,
    const unsigned short* __restrict__ v, const unsigned short* __restrict__ r,
    const float* __restrict__ tdec, const float* __restrict__ tfst,
    const float* __restrict__ pnum, const float* __restrict__ pden,
    unsigned short* __restrict__ rwkv) {
  const int gid = blockIdx.x * 256 + threadIdx.x;   // 0 .. CC*BB*HH/8-1
  const int h0 = (gid & 127) * 8;
  const int b = (gid >> 7) & (BB - 1);
  const int c = gid >> 10;
  float td[8], etf[8], num[8], den[8];
  const size_t o = (size_t)c * (BB * HH) + b * HH + h0;
#pragma unroll
  for (int j = 0; j < 8; ++j) {
    td[j] = __expf(-__expf(tdec[h0 + j]));
    etf[j] = __expf(tfst[h0 + j]);
    num[j] = pnum[o + j]; den[j] = pden[o + j];
  }
  size_t idx = (size_t)b * TT * HH + (size_t)(c * LL) * HH + h0;
#pragma unroll 2
  for (int i = 0; i < LL; ++i, idx += HH) {
    const u16x8 k8 = *(const u16x8*)(k + idx);
    const u16x8 v8 = *(const u16x8*)(v + idx);
    const u16x8 r8 = *(const u16x8*)(r + idx);
    u16x8 o8;
#pragma unroll
    for (int j = 0; j < 8; ++j) {
      const float ek = __expf(bf2f(k8[j]));
      const float vt = bf2f(v8[j]);
      const float rt = bf2f(r8[j]);
      const float e = ek * etf[j];                   // exp(tf + k) = exp(k)*exp(tf)
      const float inv = __builtin_amdgcn_rcpf(den[j] + e);
      const float outv = (num[j] + e * vt) * inv;
      num[j] = td[j] * num[j] + ek * vt;
      den[j] = td[j] * den[j] + ek;
      o8[j] = f2bf(outv * rt);
    }
    *(u16x8*)(rwkv + idx) = o8;
  }
}

extern "C" void kernel_launch(void* const* d_in, const int* in_sizes, int n_in,
                              void* d_out, int out_size, void* d_ws, size_t ws_size,
                              hipStream_t stream) {
  (void)in_sizes; (void)n_in; (void)out_size; (void)ws_size;
  const float* x    = (const float*)d_in[0];
  const float* tdec = (const float*)d_in[1];
  const float* tfst = (const float*)d_in[2];
  const float* tmk  = (const float*)d_in[3];
  const float* tmv  = (const float*)d_in[4];
  const float* tmr  = (const float*)d_in[5];
  const float* Wk   = (const float*)d_in[6];
  const float* Wv   = (const float*)d_in[7];
  const float* Wr   = (const float*)d_in[8];
  const float* Wo   = (const float*)d_in[9];
  const float* bo   = (const float*)d_in[10];
  float* out = (float*)d_out;

  char* ws = (char*)d_ws;
  const size_t MiB = (size_t)1 << 20;
  unsigned short* Wbf = (unsigned short*)(ws);             //   8 MiB
  unsigned short* kin = (unsigned short*)(ws + 8 * MiB);   //  32 MiB
  unsigned short* vin = (unsigned short*)(ws + 40 * MiB);  //  32 MiB
  unsigned short* rin = (unsigned short*)(ws + 72 * MiB);  //  32 MiB
  unsigned short* rb  = (unsigned short*)(ws + 104 * MiB); //  32 MiB  (peak 136 MiB)
  // k,v bf16 staged in d_out (64 MiB fp32 buffer = 2 x 32 MiB bf16); dead before gemm_o writes.
  unsigned short* kb = (unsigned short*)out;
  unsigned short* vb = kb + (size_t)MM * HH;
  unsigned short* rwkv = kin;                  // kin dead after gemm_kvr
  float* pnum = (float*)(ws + 40 * MiB);       // vin dead after gemm_kvr (4 MiB @ CC=128)
  float* pden = (float*)(ws + 44 * MiB);       // (4 MiB)

  hipLaunchKernelGGL(prep, dim3(20480), dim3(256), 0, stream,
                     x, tmk, tmv, tmr, Wk, Wv, Wr, Wo, kin, vin, rin, Wbf);
  hipLaunchKernelGGL(gemm_kvr, dim3(256, 3), dim3(512), 0, stream,
                     kin, vin, rin, Wbf, kb, vb, rb);
  hipLaunchKernelGGL(wkv_part, dim3(512), dim3(256), 0, stream,
                     kb, vb, tdec, pnum, pden);
  hipLaunchKernelGGL(wkv_scan, dim3(32), dim3(256), 0, stream,
                     tdec, pnum, pden);
  hipLaunchKernelGGL(wkv_final, dim3(512), dim3(256), 0, stream,
                     kb, vb, rb, tdec, tfst, pnum, pden, rwkv);
  hipLaunchKernelGGL(gemm_o, dim3(256), dim3(512), 0, stream,
                     rwkv, Wbf + (size_t)3 * HH * HH, bo, out);
}